// Round 1
// baseline (1063.546 us; speedup 1.0000x reference)
//
#include <hip/hip_runtime.h>
#include <hip/hip_bf16.h>

// ---------------------------------------------------------------------------
// GCN forward: out = A_hat @ ( (relu(A_hat @ (X@W1))) @ W2 )
// A_hat = D^-1/2 (A) D^-1/2, edges given as (row, col) pairs incl. self loops.
//
// Pipeline (all on `stream`):
//   1. memset deg=0 ; count degrees (int atomics)
//   2. dinv[i] = 1/sqrt(deg[i])
//   3. single-block exclusive scan -> row_ptr (and cnt copy)
//   4. scatter edges into CSR slots (atomic slot counter), w_e = dinv[r]*dinv[c]
//   5. GEMM1: XW1 = X @ W1            (fp32 LDS-tiled)
//   6. SpMM1: H = relu(A_hat @ XW1)   (wave-per-row, no atomics)
//   7. GEMM2: HW2 = H @ W2
//   8. SpMM2: out = A_hat @ HW2
// ---------------------------------------------------------------------------

__global__ void count_deg_kernel(const int* __restrict__ rows, int* __restrict__ deg, int E) {
    int i = blockIdx.x * blockDim.x + threadIdx.x;
    if (i < E) atomicAdd(&deg[rows[i]], 1);
}

__global__ void dinv_kernel(const int* __restrict__ deg, float* __restrict__ dinv, int n) {
    int i = blockIdx.x * blockDim.x + threadIdx.x;
    if (i < n) {
        float d = (float)deg[i];
        dinv[i] = 1.0f / sqrtf(fmaxf(d, 1e-24f));
    }
}

// Single-block (1024 threads) exclusive scan of deg -> row_ptr[0..n], cnt copy.
__global__ void scan_exclusive_kernel(const int* __restrict__ deg,
                                      int* __restrict__ row_ptr,
                                      int* __restrict__ cnt, int n) {
    __shared__ int sums[1024];
    int t = threadIdx.x;
    int chunk = (n + 1023) >> 10;
    int start = t * chunk;
    int end   = min(start + chunk, n);
    int s = 0;
    for (int i = start; i < end; i++) s += deg[i];
    sums[t] = s;
    __syncthreads();
    // Hillis-Steele inclusive scan over 1024 partials
    for (int off = 1; off < 1024; off <<= 1) {
        int v = (t >= off) ? sums[t - off] : 0;
        __syncthreads();
        sums[t] += v;
        __syncthreads();
    }
    int total = sums[1023];
    int run = (t == 0) ? 0 : sums[t - 1];
    for (int i = start; i < end; i++) {
        row_ptr[i] = run;
        cnt[i] = run;
        run += deg[i];
    }
    if (t == 0) row_ptr[n] = total;
}

__global__ void fill_csr_kernel(const int* __restrict__ rows, const int* __restrict__ colsIn,
                                const float* __restrict__ dinv, int* __restrict__ cnt,
                                int* __restrict__ csr_col, float* __restrict__ csr_w, int E) {
    int i = blockIdx.x * blockDim.x + threadIdx.x;
    if (i >= E) return;
    int r = rows[i];
    int c = colsIn[i];
    int pos = atomicAdd(&cnt[r], 1);
    csr_col[pos] = c;
    csr_w[pos]   = dinv[r] * dinv[c];
}

// fp32 tiled GEMM: C[M,N] = A[M,K] @ B[K,N], optional fused relu.
// blockDim = 256. Each thread computes TM x TN outputs. BN/TN * (BM/TM) == 256.
template <int BM, int BN, int BK, int TM, int TN>
__global__ __launch_bounds__(256) void gemm_f32_kernel(
    const float* __restrict__ A, const float* __restrict__ B, float* __restrict__ C,
    int M, int K, int N, int relu) {
    __shared__ float As[BM][BK + 1];
    __shared__ float Bs[BK][BN];
    constexpr int NCT = BN / TN;  // threads across column dim
    int tid  = threadIdx.x;
    int tcol = tid % NCT;
    int trow = tid / NCT;
    int row0 = blockIdx.x * BM;

    float acc[TM][TN];
#pragma unroll
    for (int i = 0; i < TM; i++)
#pragma unroll
        for (int j = 0; j < TN; j++) acc[i][j] = 0.f;

    for (int k0 = 0; k0 < K; k0 += BK) {
        for (int idx = tid; idx < BM * BK; idx += 256) {
            int r = idx / BK, c = idx % BK;
            int gr = row0 + r;
            As[r][c] = (gr < M) ? A[(size_t)gr * K + k0 + c] : 0.f;
        }
        for (int idx = tid; idx < BK * BN; idx += 256) {
            int r = idx / BN, c = idx % BN;
            Bs[r][c] = B[(size_t)(k0 + r) * N + c];
        }
        __syncthreads();
#pragma unroll
        for (int kk = 0; kk < BK; kk++) {
            float a[TM], b[TN];
#pragma unroll
            for (int i = 0; i < TM; i++) a[i] = As[trow * TM + i][kk];
#pragma unroll
            for (int j = 0; j < TN; j++) b[j] = Bs[kk][tcol * TN + j];
#pragma unroll
            for (int i = 0; i < TM; i++)
#pragma unroll
                for (int j = 0; j < TN; j++) acc[i][j] += a[i] * b[j];
        }
        __syncthreads();
    }

#pragma unroll
    for (int i = 0; i < TM; i++) {
        int gr = row0 + trow * TM + i;
        if (gr < M) {
#pragma unroll
            for (int j = 0; j < TN; j++) {
                float v = acc[i][j];
                C[(size_t)gr * N + tcol * TN + j] = relu ? fmaxf(v, 0.f) : v;
            }
        }
    }
}

// Wave-per-row CSR SpMM. F = VPL*64 features; each lane accumulates VPL floats.
template <int VPL>
__global__ __launch_bounds__(256) void spmm_kernel(
    const int* __restrict__ row_ptr, const int* __restrict__ cols,
    const float* __restrict__ wts, const float* __restrict__ Xin,
    float* __restrict__ Yout, int n, int relu) {
    int wave = (int)((blockIdx.x * blockDim.x + threadIdx.x) >> 6);
    int lane = threadIdx.x & 63;
    if (wave >= n) return;
    constexpr int F = VPL * 64;
    int beg = row_ptr[wave];
    int end = row_ptr[wave + 1];
    float acc[VPL];
#pragma unroll
    for (int v = 0; v < VPL; v++) acc[v] = 0.f;
    for (int e = beg; e < end; e++) {
        int c   = cols[e];
        float w = wts[e];
        const float* xp = Xin + (size_t)c * F + lane * VPL;
#pragma unroll
        for (int v = 0; v < VPL; v++) acc[v] += w * xp[v];
    }
    float* yp = Yout + (size_t)wave * F + lane * VPL;
#pragma unroll
    for (int v = 0; v < VPL; v++) yp[v] = relu ? fmaxf(acc[v], 0.f) : acc[v];
}

extern "C" void kernel_launch(void* const* d_in, const int* in_sizes, int n_in,
                              void* d_out, int out_size, void* d_ws, size_t ws_size,
                              hipStream_t stream) {
    const float* X  = (const float*)d_in[0];
    const float* W1 = (const float*)d_in[1];
    const float* W2 = (const float*)d_in[2];
    const int* erow = (const int*)d_in[3];
    const int* ecol = (const int*)d_in[4];

    const int N = in_sizes[0] / 256;  // 100000
    const int E = in_sizes[3];        // 1700000

    // Workspace carve-up (256B aligned)
    char* ws = (char*)d_ws;
    size_t off = 0;
    auto carve = [&](size_t bytes) -> char* {
        char* p = ws + off;
        off += (bytes + 255) & ~(size_t)255;
        return p;
    };
    int*   deg     = (int*)  carve((size_t)N * 4);
    float* dinv    = (float*)carve((size_t)N * 4);
    int*   row_ptr = (int*)  carve((size_t)(N + 1) * 4);
    int*   cnt     = (int*)  carve((size_t)N * 4);
    int*   csr_col = (int*)  carve((size_t)E * 4);
    float* csr_w   = (float*)carve((size_t)E * 4);
    float* XW1     = (float*)carve((size_t)N * 128 * 4);
    float* H       = (float*)carve((size_t)N * 128 * 4);
    float* HW2     = (float*)carve((size_t)N * 64 * 4);

    // 1-4: graph normalization + CSR build
    hipMemsetAsync(deg, 0, (size_t)N * 4, stream);
    count_deg_kernel<<<(E + 255) / 256, 256, 0, stream>>>(erow, deg, E);
    dinv_kernel<<<(N + 255) / 256, 256, 0, stream>>>(deg, dinv, N);
    scan_exclusive_kernel<<<1, 1024, 0, stream>>>(deg, row_ptr, cnt, N);
    fill_csr_kernel<<<(E + 255) / 256, 256, 0, stream>>>(erow, ecol, dinv, cnt, csr_col, csr_w, E);

    // 5: XW1 = X @ W1   (M=N, K=256, Ncol=128)
    gemm_f32_kernel<64, 128, 32, 8, 4><<<(N + 63) / 64, 256, 0, stream>>>(
        X, W1, XW1, N, 256, 128, 0);

    // 6: H = relu(A_hat @ XW1)   (F=128)
    spmm_kernel<2><<<(N + 3) / 4, 256, 0, stream>>>(row_ptr, csr_col, csr_w, XW1, H, N, 1);

    // 7: HW2 = H @ W2   (M=N, K=128, Ncol=64)
    gemm_f32_kernel<64, 64, 32, 8, 2><<<(N + 63) / 64, 256, 0, stream>>>(
        H, W2, HW2, N, 128, 64, 0);

    // 8: out = A_hat @ HW2   (F=64)
    spmm_kernel<1><<<(N + 3) / 4, 256, 0, stream>>>(row_ptr, csr_col, csr_w, HW2, (float*)d_out, N, 0);
}

// Round 2
// 839.566 us; speedup vs baseline: 1.2668x; 1.2668x over previous
//
#include <hip/hip_runtime.h>
#include <hip/hip_bf16.h>

// ---------------------------------------------------------------------------
// GCN forward: out = A_hat @ ( (relu(A_hat @ (X@W1))) @ W2 )
// A_hat = D^-1/2 (A) D^-1/2, edges given as (row, col) pairs incl. self loops.
//
// Pipeline (all on `stream`):
//   1. memset deg=0 ; count degrees (int atomics)
//   2. dinv[i] = 1/sqrt(deg[i])
//   3. device-wide 3-phase exclusive scan -> row_ptr (and cnt copy)
//      (R1: replaced single-block scan, was 232 us on 1 CU)
//   4. scatter edges into CSR slots (atomic slot counter), w_e = dinv[r]*dinv[c]
//   5. GEMM1: XW1 = X @ W1            (fp32 LDS-tiled)
//   6. SpMM1: H = relu(A_hat @ XW1)   (wave-per-row, no atomics)
//   7. GEMM2: HW2 = H @ W2
//   8. SpMM2: out = A_hat @ HW2
// ---------------------------------------------------------------------------

__global__ void count_deg_kernel(const int* __restrict__ rows, int* __restrict__ deg, int E) {
    int i = blockIdx.x * blockDim.x + threadIdx.x;
    if (i < E) atomicAdd(&deg[rows[i]], 1);
}

__global__ void dinv_kernel(const int* __restrict__ deg, float* __restrict__ dinv, int n) {
    int i = blockIdx.x * blockDim.x + threadIdx.x;
    if (i < n) {
        float d = (float)deg[i];
        dinv[i] = 1.0f / sqrtf(fmaxf(d, 1e-24f));
    }
}

// ---- 3-phase device-wide exclusive scan (1024 elements per block) ----------
// phase1: within-block exclusive prefix -> row_ptr, block totals -> block_total
__global__ __launch_bounds__(256) void scan_phase1_kernel(
    const int* __restrict__ deg, int* __restrict__ row_ptr,
    int* __restrict__ block_total, int n) {
    __shared__ int tsum[256];
    int t = threadIdx.x;
    int base = blockIdx.x * 1024 + t * 4;
    int v0 = (base + 0 < n) ? deg[base + 0] : 0;
    int v1 = (base + 1 < n) ? deg[base + 1] : 0;
    int v2 = (base + 2 < n) ? deg[base + 2] : 0;
    int v3 = (base + 3 < n) ? deg[base + 3] : 0;
    tsum[t] = v0 + v1 + v2 + v3;
    __syncthreads();
    for (int off = 1; off < 256; off <<= 1) {
        int x = (t >= off) ? tsum[t - off] : 0;
        __syncthreads();
        tsum[t] += x;
        __syncthreads();
    }
    if (t == 255) block_total[blockIdx.x] = tsum[255];
    int run = (t == 0) ? 0 : tsum[t - 1];
    if (base + 0 < n) row_ptr[base + 0] = run; run += v0;
    if (base + 1 < n) row_ptr[base + 1] = run; run += v1;
    if (base + 2 < n) row_ptr[base + 2] = run; run += v2;
    if (base + 3 < n) row_ptr[base + 3] = run;
}

// phase2: single small block scans G (<=256) block totals -> exclusive offsets,
// total stored at block_offset[G].
__global__ __launch_bounds__(256) void scan_phase2_kernel(
    const int* __restrict__ block_total, int* __restrict__ block_offset, int G) {
    __shared__ int s[256];
    int t = threadIdx.x;
    s[t] = (t < G) ? block_total[t] : 0;
    __syncthreads();
    for (int off = 1; off < 256; off <<= 1) {
        int x = (t >= off) ? s[t - off] : 0;
        __syncthreads();
        s[t] += x;
        __syncthreads();
    }
    if (t < G) block_offset[t] = (t == 0) ? 0 : s[t - 1];
    if (t == 0) block_offset[G] = s[255];
}

// phase3: add block offsets, mirror into cnt, write row_ptr[n] = total.
__global__ __launch_bounds__(256) void scan_phase3_kernel(
    int* __restrict__ row_ptr, int* __restrict__ cnt,
    const int* __restrict__ block_offset, int n, int G) {
    int i = blockIdx.x * blockDim.x + threadIdx.x;
    if (i < n) {
        int v = row_ptr[i] + block_offset[i >> 10];
        row_ptr[i] = v;
        cnt[i] = v;
    }
    if (i == 0) row_ptr[n] = block_offset[G];
}

__global__ void fill_csr_kernel(const int* __restrict__ rows, const int* __restrict__ colsIn,
                                const float* __restrict__ dinv, int* __restrict__ cnt,
                                int* __restrict__ csr_col, float* __restrict__ csr_w, int E) {
    int i = blockIdx.x * blockDim.x + threadIdx.x;
    if (i >= E) return;
    int r = rows[i];
    int c = colsIn[i];
    int pos = atomicAdd(&cnt[r], 1);
    csr_col[pos] = c;
    csr_w[pos]   = dinv[r] * dinv[c];
}

// fp32 tiled GEMM: C[M,N] = A[M,K] @ B[K,N], optional fused relu.
// blockDim = 256. Each thread computes TM x TN outputs. BN/TN * (BM/TM) == 256.
template <int BM, int BN, int BK, int TM, int TN>
__global__ __launch_bounds__(256) void gemm_f32_kernel(
    const float* __restrict__ A, const float* __restrict__ B, float* __restrict__ C,
    int M, int K, int N, int relu) {
    __shared__ float As[BM][BK + 1];
    __shared__ float Bs[BK][BN];
    constexpr int NCT = BN / TN;  // threads across column dim
    int tid  = threadIdx.x;
    int tcol = tid % NCT;
    int trow = tid / NCT;
    int row0 = blockIdx.x * BM;

    float acc[TM][TN];
#pragma unroll
    for (int i = 0; i < TM; i++)
#pragma unroll
        for (int j = 0; j < TN; j++) acc[i][j] = 0.f;

    for (int k0 = 0; k0 < K; k0 += BK) {
        for (int idx = tid; idx < BM * BK; idx += 256) {
            int r = idx / BK, c = idx % BK;
            int gr = row0 + r;
            As[r][c] = (gr < M) ? A[(size_t)gr * K + k0 + c] : 0.f;
        }
        for (int idx = tid; idx < BK * BN; idx += 256) {
            int r = idx / BN, c = idx % BN;
            Bs[r][c] = B[(size_t)(k0 + r) * N + c];
        }
        __syncthreads();
#pragma unroll
        for (int kk = 0; kk < BK; kk++) {
            float a[TM], b[TN];
#pragma unroll
            for (int i = 0; i < TM; i++) a[i] = As[trow * TM + i][kk];
#pragma unroll
            for (int j = 0; j < TN; j++) b[j] = Bs[kk][tcol * TN + j];
#pragma unroll
            for (int i = 0; i < TM; i++)
#pragma unroll
                for (int j = 0; j < TN; j++) acc[i][j] += a[i] * b[j];
        }
        __syncthreads();
    }

#pragma unroll
    for (int i = 0; i < TM; i++) {
        int gr = row0 + trow * TM + i;
        if (gr < M) {
#pragma unroll
            for (int j = 0; j < TN; j++) {
                float v = acc[i][j];
                C[(size_t)gr * N + tcol * TN + j] = relu ? fmaxf(v, 0.f) : v;
            }
        }
    }
}

// Wave-per-row CSR SpMM. F = VPL*64 features; each lane accumulates VPL floats.
template <int VPL>
__global__ __launch_bounds__(256) void spmm_kernel(
    const int* __restrict__ row_ptr, const int* __restrict__ cols,
    const float* __restrict__ wts, const float* __restrict__ Xin,
    float* __restrict__ Yout, int n, int relu) {
    int wave = (int)((blockIdx.x * blockDim.x + threadIdx.x) >> 6);
    int lane = threadIdx.x & 63;
    if (wave >= n) return;
    constexpr int F = VPL * 64;
    int beg = row_ptr[wave];
    int end = row_ptr[wave + 1];
    float acc[VPL];
#pragma unroll
    for (int v = 0; v < VPL; v++) acc[v] = 0.f;
    for (int e = beg; e < end; e++) {
        int c   = cols[e];
        float w = wts[e];
        const float* xp = Xin + (size_t)c * F + lane * VPL;
#pragma unroll
        for (int v = 0; v < VPL; v++) acc[v] += w * xp[v];
    }
    float* yp = Yout + (size_t)wave * F + lane * VPL;
#pragma unroll
    for (int v = 0; v < VPL; v++) yp[v] = relu ? fmaxf(acc[v], 0.f) : acc[v];
}

extern "C" void kernel_launch(void* const* d_in, const int* in_sizes, int n_in,
                              void* d_out, int out_size, void* d_ws, size_t ws_size,
                              hipStream_t stream) {
    const float* X  = (const float*)d_in[0];
    const float* W1 = (const float*)d_in[1];
    const float* W2 = (const float*)d_in[2];
    const int* erow = (const int*)d_in[3];
    const int* ecol = (const int*)d_in[4];

    const int N = in_sizes[0] / 256;  // 100000
    const int E = in_sizes[3];        // 1700000
    const int G = (N + 1023) >> 10;   // scan blocks (98 <= 256)

    // Workspace carve-up (256B aligned)
    char* ws = (char*)d_ws;
    size_t off = 0;
    auto carve = [&](size_t bytes) -> char* {
        char* p = ws + off;
        off += (bytes + 255) & ~(size_t)255;
        return p;
    };
    int*   deg       = (int*)  carve((size_t)N * 4);
    float* dinv      = (float*)carve((size_t)N * 4);
    int*   row_ptr   = (int*)  carve((size_t)(N + 1) * 4);
    int*   cnt       = (int*)  carve((size_t)N * 4);
    int*   blk_total = (int*)  carve((size_t)G * 4);
    int*   blk_off   = (int*)  carve((size_t)(G + 1) * 4);
    int*   csr_col   = (int*)  carve((size_t)E * 4);
    float* csr_w     = (float*)carve((size_t)E * 4);
    float* XW1       = (float*)carve((size_t)N * 128 * 4);
    float* H         = (float*)carve((size_t)N * 128 * 4);
    float* HW2       = (float*)carve((size_t)N * 64 * 4);

    // 1-4: graph normalization + CSR build
    hipMemsetAsync(deg, 0, (size_t)N * 4, stream);
    count_deg_kernel<<<(E + 255) / 256, 256, 0, stream>>>(erow, deg, E);
    dinv_kernel<<<(N + 255) / 256, 256, 0, stream>>>(deg, dinv, N);
    scan_phase1_kernel<<<G, 256, 0, stream>>>(deg, row_ptr, blk_total, N);
    scan_phase2_kernel<<<1, 256, 0, stream>>>(blk_total, blk_off, G);
    scan_phase3_kernel<<<(N + 255) / 256, 256, 0, stream>>>(row_ptr, cnt, blk_off, N, G);
    fill_csr_kernel<<<(E + 255) / 256, 256, 0, stream>>>(erow, ecol, dinv, cnt, csr_col, csr_w, E);

    // 5: XW1 = X @ W1   (M=N, K=256, Ncol=128)
    gemm_f32_kernel<64, 128, 32, 8, 4><<<(N + 63) / 64, 256, 0, stream>>>(
        X, W1, XW1, N, 256, 128, 0);

    // 6: H = relu(A_hat @ XW1)   (F=128)
    spmm_kernel<2><<<(N + 3) / 4, 256, 0, stream>>>(row_ptr, csr_col, csr_w, XW1, H, N, 1);

    // 7: HW2 = H @ W2   (M=N, K=128, Ncol=64)
    gemm_f32_kernel<64, 64, 32, 8, 2><<<(N + 63) / 64, 256, 0, stream>>>(
        H, W2, HW2, N, 128, 64, 0);

    // 8: out = A_hat @ HW2   (F=64)
    spmm_kernel<1><<<(N + 3) / 4, 256, 0, stream>>>(row_ptr, csr_col, csr_w, HW2, (float*)d_out, N, 0);
}

// Round 3
// 512.222 us; speedup vs baseline: 2.0763x; 1.6391x over previous
//
#include <hip/hip_runtime.h>
#include <hip/hip_bf16.h>

// ---------------------------------------------------------------------------
// GCN forward: out = A_hat @ ( (relu(A_hat @ (X@W1))) @ W2 )
// A_hat = D^-1/2 (A) D^-1/2, edges given as (row, col) pairs incl. self loops.
//
// R2: internal tensors (XW1, H, HW2, W1, W2) in bf16; GEMMs on MFMA
//     16x16x32_bf16; SpMM gathers bf16 (halves fetch bytes), accumulates fp32.
//     Final output fp32.
// ---------------------------------------------------------------------------

typedef __attribute__((ext_vector_type(8))) short short8;
typedef __attribute__((ext_vector_type(4))) float floatx4;

static __device__ __forceinline__ ushort f32_to_bf16_bits(float f) {
    union { ushort u; __hip_bfloat16 b; } cv;
    cv.b = __float2bfloat16(f);
    return cv.u;
}
static __device__ __forceinline__ float bf16lo_to_f32(uint u) {
    return __uint_as_float(u << 16);
}
static __device__ __forceinline__ float bf16hi_to_f32(uint u) {
    return __uint_as_float(u & 0xffff0000u);
}

// ---------------- graph prep --------------------------------------------

__global__ void count_deg_kernel(const int* __restrict__ rows, int* __restrict__ deg, int E) {
    int i = blockIdx.x * blockDim.x + threadIdx.x;
    if (i < E) atomicAdd(&deg[rows[i]], 1);
}

__global__ void dinv_kernel(const int* __restrict__ deg, float* __restrict__ dinv, int n) {
    int i = blockIdx.x * blockDim.x + threadIdx.x;
    if (i < n) {
        float d = (float)deg[i];
        dinv[i] = 1.0f / sqrtf(fmaxf(d, 1e-24f));
    }
}

__global__ __launch_bounds__(256) void scan_phase1_kernel(
    const int* __restrict__ deg, int* __restrict__ row_ptr,
    int* __restrict__ block_total, int n) {
    __shared__ int tsum[256];
    int t = threadIdx.x;
    int base = blockIdx.x * 1024 + t * 4;
    int v0 = (base + 0 < n) ? deg[base + 0] : 0;
    int v1 = (base + 1 < n) ? deg[base + 1] : 0;
    int v2 = (base + 2 < n) ? deg[base + 2] : 0;
    int v3 = (base + 3 < n) ? deg[base + 3] : 0;
    tsum[t] = v0 + v1 + v2 + v3;
    __syncthreads();
    for (int off = 1; off < 256; off <<= 1) {
        int x = (t >= off) ? tsum[t - off] : 0;
        __syncthreads();
        tsum[t] += x;
        __syncthreads();
    }
    if (t == 255) block_total[blockIdx.x] = tsum[255];
    int run = (t == 0) ? 0 : tsum[t - 1];
    if (base + 0 < n) row_ptr[base + 0] = run; run += v0;
    if (base + 1 < n) row_ptr[base + 1] = run; run += v1;
    if (base + 2 < n) row_ptr[base + 2] = run; run += v2;
    if (base + 3 < n) row_ptr[base + 3] = run;
}

__global__ __launch_bounds__(256) void scan_phase2_kernel(
    const int* __restrict__ block_total, int* __restrict__ block_offset, int G) {
    __shared__ int s[256];
    int t = threadIdx.x;
    s[t] = (t < G) ? block_total[t] : 0;
    __syncthreads();
    for (int off = 1; off < 256; off <<= 1) {
        int x = (t >= off) ? s[t - off] : 0;
        __syncthreads();
        s[t] += x;
        __syncthreads();
    }
    if (t < G) block_offset[t] = (t == 0) ? 0 : s[t - 1];
    if (t == 0) block_offset[G] = s[255];
}

__global__ __launch_bounds__(256) void scan_phase3_kernel(
    int* __restrict__ row_ptr, int* __restrict__ cnt,
    const int* __restrict__ block_offset, int n, int G) {
    int i = blockIdx.x * blockDim.x + threadIdx.x;
    if (i < n) {
        int v = row_ptr[i] + block_offset[i >> 10];
        row_ptr[i] = v;
        cnt[i] = v;
    }
    if (i == 0) row_ptr[n] = block_offset[G];
}

__global__ void fill_csr_kernel(const int* __restrict__ rows, const int* __restrict__ colsIn,
                                const float* __restrict__ dinv, int* __restrict__ cnt,
                                int* __restrict__ csr_col, float* __restrict__ csr_w, int E) {
    int i = blockIdx.x * blockDim.x + threadIdx.x;
    if (i >= E) return;
    int r = rows[i];
    int c = colsIn[i];
    int pos = atomicAdd(&cnt[r], 1);
    csr_col[pos] = c;
    csr_w[pos]   = dinv[r] * dinv[c];
}

// ---------------- weight cast + transpose --------------------------------
// out[n][k] = bf16(in[k][n]);  in is [K][Ncols] fp32 row-major.
__global__ void cast_transpose_kernel(const float* __restrict__ in, ushort* __restrict__ out,
                                      int K, int Ncols) {
    int i = blockIdx.x * blockDim.x + threadIdx.x;  // i = n*K + k
    if (i >= K * Ncols) return;
    int n = i / K, k = i % K;
    out[i] = f32_to_bf16_bits(in[(size_t)k * Ncols + n]);
}

// ---------------- MFMA GEMM ----------------------------------------------
// C[M,NCOLS](bf16) = A[M,KTOT] @ Bt^T, Bt is [NCOLS][KTOT] bf16 (pre-transposed).
// A fp32 (converted in-register) if AF32, else bf16.
// Block: 256 thr = 4 waves; tile 64 rows x NCOLS cols; wave w -> rows 16w..16w+15.
// MFMA layouts (HW-verified per guide m89/m120):
//   a_frag lane l: A[m=l&15][k=(l>>4)*8+j]
//   b_frag lane l: B[k=(l>>4)*8+j][n=l&15]
//   d      lane l: D[row=(l>>4)*4+r][col=l&15]
template <int KTOT, int NCOLS, bool AF32>
__global__ __launch_bounds__(256) void gemm_mfma_kernel(
    const void* __restrict__ Aptr, const ushort* __restrict__ Bt,
    ushort* __restrict__ Cbf, int M) {
    constexpr int KP = 128;           // K panel in LDS
    constexpr int COLT = NCOLS / 16;  // 8 (gemm1) or 4 (gemm2)
    __shared__ ushort Bs[NCOLS][KP + 8];
    int tid = threadIdx.x;
    int wave = tid >> 6, lane = tid & 63;
    int quad = lane >> 4, l16 = lane & 15;
    int row0 = blockIdx.x * 64;
    int rowA = row0 + wave * 16 + l16;
    int rowAc = min(rowA, M - 1);

    floatx4 acc[COLT];
#pragma unroll
    for (int t = 0; t < COLT; t++) acc[t] = (floatx4){0.f, 0.f, 0.f, 0.f};

    for (int kp = 0; kp < KTOT; kp += KP) {
        // stage B panel: Bs[n][k] = Bt[n][kp+k], coalesced 16B units
        for (int u = tid; u < NCOLS * (KP / 8); u += 256) {
            int n = u / (KP / 8);
            int k8 = (u % (KP / 8)) * 8;
            *(short8*)&Bs[n][k8] = *(const short8*)(Bt + (size_t)n * KTOT + kp + k8);
        }
        __syncthreads();
#pragma unroll
        for (int kc = 0; kc < KP / 32; kc++) {
            int kk = kp + kc * 32 + quad * 8;
            short8 a;
            if (AF32) {
                const float* ap = (const float*)Aptr + (size_t)rowAc * KTOT + kk;
#pragma unroll
                for (int j = 0; j < 8; j++) a[j] = (short)f32_to_bf16_bits(ap[j]);
            } else {
                a = *(const short8*)((const ushort*)Aptr + (size_t)rowAc * KTOT + kk);
            }
#pragma unroll
            for (int t = 0; t < COLT; t++) {
                short8 b = *(const short8*)&Bs[t * 16 + l16][kc * 32 + quad * 8];
                acc[t] = __builtin_amdgcn_mfma_f32_16x16x32_bf16(a, b, acc[t], 0, 0, 0);
            }
        }
        __syncthreads();
    }

#pragma unroll
    for (int t = 0; t < COLT; t++) {
#pragma unroll
        for (int r = 0; r < 4; r++) {
            int row = row0 + wave * 16 + quad * 4 + r;
            if (row < M)
                Cbf[(size_t)row * NCOLS + t * 16 + l16] = f32_to_bf16_bits(acc[t][r]);
        }
    }
}

// ---------------- SpMM (bf16 gather, fp32 accumulate) ---------------------
// F=128: wave per row, lane holds 2 features (one dword gather per edge).
__global__ __launch_bounds__(256) void spmm_bf16_f128_kernel(
    const int* __restrict__ row_ptr, const int* __restrict__ cols,
    const float* __restrict__ wts, const ushort* __restrict__ Xin,
    ushort* __restrict__ Yout, int n) {
    int wv = (int)((blockIdx.x * 256 + threadIdx.x) >> 6);
    int lane = threadIdx.x & 63;
    if (wv >= n) return;
    int beg = row_ptr[wv], end = row_ptr[wv + 1];
    float a0 = 0.f, a1 = 0.f;
    int e = beg;
    for (; e + 4 <= end; e += 4) {
        int c0 = cols[e], c1 = cols[e + 1], c2 = cols[e + 2], c3 = cols[e + 3];
        float w0 = wts[e], w1 = wts[e + 1], w2 = wts[e + 2], w3 = wts[e + 3];
        uint u0 = *(const uint*)(Xin + (size_t)c0 * 128 + lane * 2);
        uint u1 = *(const uint*)(Xin + (size_t)c1 * 128 + lane * 2);
        uint u2 = *(const uint*)(Xin + (size_t)c2 * 128 + lane * 2);
        uint u3 = *(const uint*)(Xin + (size_t)c3 * 128 + lane * 2);
        a0 += w0 * bf16lo_to_f32(u0); a1 += w0 * bf16hi_to_f32(u0);
        a0 += w1 * bf16lo_to_f32(u1); a1 += w1 * bf16hi_to_f32(u1);
        a0 += w2 * bf16lo_to_f32(u2); a1 += w2 * bf16hi_to_f32(u2);
        a0 += w3 * bf16lo_to_f32(u3); a1 += w3 * bf16hi_to_f32(u3);
    }
    for (; e < end; e++) {
        int c = cols[e];
        float w = wts[e];
        uint u = *(const uint*)(Xin + (size_t)c * 128 + lane * 2);
        a0 += w * bf16lo_to_f32(u);
        a1 += w * bf16hi_to_f32(u);
    }
    a0 = fmaxf(a0, 0.f);  // relu (layer 1 only uses this kernel)
    a1 = fmaxf(a1, 0.f);
    uint out = (uint)f32_to_bf16_bits(a0) | ((uint)f32_to_bf16_bits(a1) << 16);
    *(uint*)(Yout + (size_t)wv * 128 + lane * 2) = out;
}

// F=64: wave per row, lane holds 1 feature (ushort gather), fp32 output.
__global__ __launch_bounds__(256) void spmm_bf16_f64_kernel(
    const int* __restrict__ row_ptr, const int* __restrict__ cols,
    const float* __restrict__ wts, const ushort* __restrict__ Xin,
    float* __restrict__ Yout, int n) {
    int wv = (int)((blockIdx.x * 256 + threadIdx.x) >> 6);
    int lane = threadIdx.x & 63;
    if (wv >= n) return;
    int beg = row_ptr[wv], end = row_ptr[wv + 1];
    float acc = 0.f;
    int e = beg;
    for (; e + 4 <= end; e += 4) {
        int c0 = cols[e], c1 = cols[e + 1], c2 = cols[e + 2], c3 = cols[e + 3];
        float w0 = wts[e], w1 = wts[e + 1], w2 = wts[e + 2], w3 = wts[e + 3];
        uint u0 = Xin[(size_t)c0 * 64 + lane];
        uint u1 = Xin[(size_t)c1 * 64 + lane];
        uint u2 = Xin[(size_t)c2 * 64 + lane];
        uint u3 = Xin[(size_t)c3 * 64 + lane];
        acc += w0 * bf16lo_to_f32(u0);
        acc += w1 * bf16lo_to_f32(u1);
        acc += w2 * bf16lo_to_f32(u2);
        acc += w3 * bf16lo_to_f32(u3);
    }
    for (; e < end; e++) {
        uint u = Xin[(size_t)cols[e] * 64 + lane];
        acc += wts[e] * bf16lo_to_f32(u);
    }
    Yout[(size_t)wv * 64 + lane] = acc;
}

// ---------------- launch ---------------------------------------------------

extern "C" void kernel_launch(void* const* d_in, const int* in_sizes, int n_in,
                              void* d_out, int out_size, void* d_ws, size_t ws_size,
                              hipStream_t stream) {
    const float* X  = (const float*)d_in[0];
    const float* W1 = (const float*)d_in[1];
    const float* W2 = (const float*)d_in[2];
    const int* erow = (const int*)d_in[3];
    const int* ecol = (const int*)d_in[4];

    const int N = in_sizes[0] / 256;  // 100000
    const int E = in_sizes[3];        // 1700000
    const int G = (N + 1023) >> 10;   // scan blocks (98 <= 256)

    char* ws = (char*)d_ws;
    size_t off = 0;
    auto carve = [&](size_t bytes) -> char* {
        char* p = ws + off;
        off += (bytes + 255) & ~(size_t)255;
        return p;
    };
    int*    deg       = (int*)   carve((size_t)N * 4);
    float*  dinv      = (float*) carve((size_t)N * 4);
    int*    row_ptr   = (int*)   carve((size_t)(N + 1) * 4);
    int*    cnt       = (int*)   carve((size_t)N * 4);
    int*    blk_total = (int*)   carve((size_t)G * 4);
    int*    blk_off   = (int*)   carve((size_t)(G + 1) * 4);
    int*    csr_col   = (int*)   carve((size_t)E * 4);
    float*  csr_w     = (float*) carve((size_t)E * 4);
    ushort* W1t       = (ushort*)carve((size_t)256 * 128 * 2);  // [128][256]
    ushort* W2t       = (ushort*)carve((size_t)128 * 64 * 2);   // [64][128]
    ushort* XW1       = (ushort*)carve((size_t)N * 128 * 2);
    ushort* H         = (ushort*)carve((size_t)N * 128 * 2);
    ushort* HW2       = (ushort*)carve((size_t)N * 64 * 2);

    // graph normalization + CSR build
    hipMemsetAsync(deg, 0, (size_t)N * 4, stream);
    count_deg_kernel<<<(E + 255) / 256, 256, 0, stream>>>(erow, deg, E);
    dinv_kernel<<<(N + 255) / 256, 256, 0, stream>>>(deg, dinv, N);
    scan_phase1_kernel<<<G, 256, 0, stream>>>(deg, row_ptr, blk_total, N);
    scan_phase2_kernel<<<1, 256, 0, stream>>>(blk_total, blk_off, G);
    scan_phase3_kernel<<<(N + 255) / 256, 256, 0, stream>>>(row_ptr, cnt, blk_off, N, G);
    fill_csr_kernel<<<(E + 255) / 256, 256, 0, stream>>>(erow, ecol, dinv, cnt, csr_col, csr_w, E);

    // weights: cast + transpose to bf16 [n][k]
    cast_transpose_kernel<<<(256 * 128 + 255) / 256, 256, 0, stream>>>(W1, W1t, 256, 128);
    cast_transpose_kernel<<<(128 * 64 + 255) / 256, 256, 0, stream>>>(W2, W2t, 128, 64);

    // GEMM1: XW1(bf16) = X(fp32->bf16) @ W1
    gemm_mfma_kernel<256, 128, true><<<(N + 63) / 64, 256, 0, stream>>>(
        (const void*)X, W1t, XW1, N);

    // SpMM1: H(bf16) = relu(A_hat @ XW1)
    spmm_bf16_f128_kernel<<<(N + 3) / 4, 256, 0, stream>>>(row_ptr, csr_col, csr_w, XW1, H, N);

    // GEMM2: HW2(bf16) = H @ W2
    gemm_mfma_kernel<128, 64, false><<<(N + 63) / 64, 256, 0, stream>>>(
        (const void*)H, W2t, HW2, N);

    // SpMM2: out(fp32) = A_hat @ HW2
    spmm_bf16_f64_kernel<<<(N + 3) / 4, 256, 0, stream>>>(row_ptr, csr_col, csr_w, HW2, (float*)d_out, N);
}